// Round 2
// baseline (34235.248 us; speedup 1.0000x reference)
//
#include <hip/hip_runtime.h>
#include <hip/hip_cooperative_groups.h>

namespace cg = cooperative_groups;

typedef __bf16 bf16x8 __attribute__((ext_vector_type(8)));
typedef float floatx4 __attribute__((ext_vector_type(4)));

#define HID 1024
#define HH (1024*1024)
#define SEQ 512
#define NB 32768  /* 32*1024 state elements */

__device__ __forceinline__ float bf2f(unsigned short u) {
  union { unsigned int i; float f; } v; v.i = ((unsigned int)u) << 16; return v.f;
}
__device__ __forceinline__ unsigned short f2bf(float f) {
  union { float f; unsigned int i; } v; v.f = f;
  unsigned int i = v.i;
  return (unsigned short)((i + 0x7fffu + ((i >> 16) & 1u)) >> 16);
}
__device__ __forceinline__ float ldflag(const void* p, long i, int flag) {
  return flag ? ((const float*)p)[i] : bf2f(((const unsigned short*)p)[i]);
}
__device__ __forceinline__ void outw(void* out, int flag, long idx, float v) {
  if (flag) ((float*)out)[idx] = v;
  else      ((unsigned short*)out)[idx] = f2bf(v);
}
__device__ __forceinline__ float sigmoidf_(float x) { return 1.0f / (1.0f + __expf(-x)); }

// ---- dtype detection: bf16 (flag=0) vs fp32 (flag=1) ----
__global__ void detect_k(const unsigned int* __restrict__ xw, int* __restrict__ flag) {
  unsigned int w = xw[threadIdx.x];
  int e = (w >> 7) & 0xFF;                 // low-half bf16 exponent field
  int ok = (e >= 100 && e <= 141) ? 1 : 0; // plausible for N(0,1) bf16 values
  unsigned long long m = __ballot(ok);
  if (threadIdx.x == 0) *flag = (__popcll(m) >= 36) ? 0 : 1;
}

// ---- fp32 -> bf16 conversion of x, 6 weight tensors, WY (no-op when flag=0) ----
__global__ void convert_k(const float* __restrict__ x,
                          const float* __restrict__ w0, const float* __restrict__ w1,
                          const float* __restrict__ w2, const float* __restrict__ w3,
                          const float* __restrict__ w4, const float* __restrict__ w5,
                          const float* __restrict__ wy,
                          unsigned short* __restrict__ xb, unsigned short* __restrict__ wc,
                          unsigned short* __restrict__ wyc, const int* __restrict__ flag) {
  if (*flag == 0) return;
  const float* Ws[6] = { w0, w1, w2, w3, w4, w5 };
  const long total = 3801088;  // (16777216 + 6*2097152 + 1048576) / 8
  for (long c = (long)blockIdx.x * 256 + threadIdx.x; c < total; c += (long)gridDim.x * 256) {
    long e = c * 8;
    const float* src; unsigned short* dst; long off;
    if (e < 16777216)      { src = x;  dst = xb;  off = e; }
    else if (e < 29360128) { long r = e - 16777216; int wi = (int)(r >> 21);
                             src = Ws[wi]; dst = wc + (long)wi * 2097152; off = r & 2097151; }
    else                   { src = wy; dst = wyc; off = e - 29360128; }
    float4 a = *(const float4*)(src + off);
    float4 b = *(const float4*)(src + off + 4);
    uint4 o;
    o.x = (unsigned)f2bf(a.x) | ((unsigned)f2bf(a.y) << 16);
    o.y = (unsigned)f2bf(a.z) | ((unsigned)f2bf(a.w) << 16);
    o.z = (unsigned)f2bf(b.x) | ((unsigned)f2bf(b.y) << 16);
    o.w = (unsigned)f2bf(b.z) | ((unsigned)f2bf(b.w) << 16);
    *(uint4*)(dst + off) = o;
  }
}

// K=1024+1024 full-K MFMA dot (one wave owns the whole K) over pre-offset pointers.
__device__ __forceinline__ floatx4 gfull2(const unsigned short* __restrict__ a1,
                                          const unsigned short* __restrict__ w1,
                                          const unsigned short* __restrict__ a2,
                                          const unsigned short* __restrict__ w2) {
  floatx4 acc = {0.f, 0.f, 0.f, 0.f};
  #pragma unroll
  for (int k = 0; k < 1024; k += 32)
    acc = __builtin_amdgcn_mfma_f32_16x16x32_bf16(*(const bf16x8*)(a1 + k),
                                                  *(const bf16x8*)(w1 + k), acc, 0, 0, 0);
  #pragma unroll
  for (int k = 0; k < 1024; k += 32)
    acc = __builtin_amdgcn_mfma_f32_16x16x32_bf16(*(const bf16x8*)(a2 + k),
                                                  *(const bf16x8*)(w2 + k), acc, 0, 0, 0);
  return acc;
}

// Cross-layer pipelined GRU. Slot s: layer0 @ step s runs concurrently with
// layer1 @ step s-1, and Y_{s-2} in the shadow of interval Q. 2 grid syncs/slot.
// Interval P: blocks 0-63: z0/r0(A_s); blocks 64-127: z1/r1(B_{s-1}).
// Interval Q: blocks 0-31: g0+h0(A_s); 32-63: g1+h1(B_{s-1}); 64-127: Y_{s-2}.
// h0b/h1b are parity double-buffered (written at parity s&1 / (s-1)&1 resp.).
__global__ void __launch_bounds__(256) gru2(
    const void* __restrict__ x, const void* __restrict__ h0i,
    const void* __restrict__ Wxz, const void* __restrict__ Wxr, const void* __restrict__ Wxg,
    const void* __restrict__ Whz, const void* __restrict__ Whr, const void* __restrict__ Whg,
    const void* __restrict__ bhz, const void* __restrict__ bhr, const void* __restrict__ bhg,
    const void* __restrict__ WY, const void* __restrict__ bY,
    void* __restrict__ out, const int* __restrict__ flagp,
    const unsigned short* __restrict__ xb, const unsigned short* __restrict__ wcv,
    const unsigned short* __restrict__ wyc,
    float* __restrict__ h0f, float* __restrict__ h1f,
    float* __restrict__ z0f, float* __restrict__ z1f,
    unsigned short* __restrict__ h0b, unsigned short* __restrict__ h1b,
    unsigned short* __restrict__ rh0, unsigned short* __restrict__ rh1)
{
  cg::grid_group grid = cg::this_grid();
  const int flag = *flagp;
  const int tid  = blockIdx.x * 256 + threadIdx.x;
  const int wave = threadIdx.x >> 6;
  const int lane = threadIdx.x & 63;
  const int l15  = lane & 15;
  const int kq   = (lane >> 4) * 8;
  const int blk  = blockIdx.x;

  const unsigned short* xP  = flag ? xb                : (const unsigned short*)x;
  const unsigned short* Wzp = flag ? wcv + 0L*2097152  : (const unsigned short*)Wxz;
  const unsigned short* Wrp = flag ? wcv + 1L*2097152  : (const unsigned short*)Wxr;
  const unsigned short* Wgp = flag ? wcv + 2L*2097152  : (const unsigned short*)Wxg;
  const unsigned short* Uzp = flag ? wcv + 3L*2097152  : (const unsigned short*)Whz;
  const unsigned short* Urp = flag ? wcv + 4L*2097152  : (const unsigned short*)Whr;
  const unsigned short* Ugp = flag ? wcv + 5L*2097152  : (const unsigned short*)Whg;
  const unsigned short* WYp = flag ? wyc               : (const unsigned short*)WY;

  // init hidden state (h_{-1}) into both parity buffers
  {
    float v0 = ldflag(h0i, tid, flag);
    float v1 = ldflag(h0i, NB + tid, flag);
    h0f[tid] = v0; h1f[tid] = v1;
    unsigned short b0 = f2bf(v0), b1 = f2bf(v1);
    h0b[tid] = b0; h0b[NB + tid] = b0;
    h1b[tid] = b1; h1b[NB + tid] = b1;
  }
  grid.sync();

  for (int s = 0; s < SEQ + 2; ++s) {
    const int pPrev = ((s + 1) & 1) * NB;  // parity slot of h_{s-1}
    const int pPrev2 = (s & 1) * NB;       // parity slot of h_{s-2}
    // ================= interval P =================
    if (blk < 64) {
      if (s < SEQ) {  // A_s: z0 / r0
        const int zr = blk >> 5;
        const int c0 = (blk & 31) * 32;
        const int mt = wave & 1, nt = wave >> 1;
        const int m = mt * 16 + l15, n = c0 + nt * 16 + l15;
        const unsigned short* a1 = xP + (long)m * (SEQ * HID) + (long)s * HID + kq;
        const unsigned short* w1 = (zr ? Wrp : Wzp) + (long)n * HID + kq;
        const unsigned short* a2 = h0b + pPrev + m * HID + kq;
        const unsigned short* w2 = (zr ? Urp : Uzp) + (long)n * HID + kq;
        floatx4 acc = gfull2(a1, w1, a2, w2);
        float bv = ldflag(zr ? bhr : bhz, n, flag);
        #pragma unroll
        for (int r = 0; r < 4; ++r) {
          int row = mt * 16 + (lane >> 4) * 4 + r;
          int idx = row * HID + n;
          float v = sigmoidf_(acc[r] + bv);
          if (zr == 0) z0f[idx] = v;
          else         rh0[idx] = f2bf(v * h0f[idx]);
        }
      }
    } else {
      if (s >= 1 && s <= SEQ) {  // B_{s-1}: z1 / r1
        const int zr = (blk - 64) >> 5;
        const int c0 = ((blk - 64) & 31) * 32;
        const int mt = wave & 1, nt = wave >> 1;
        const int m = mt * 16 + l15, n = c0 + nt * 16 + l15;
        const unsigned short* a1 = h0b + pPrev + m * HID + kq;           // h0_{s-1}
        const unsigned short* w1 = (zr ? Wrp : Wzp) + HH + (long)n * HID + kq;
        const unsigned short* a2 = h1b + pPrev2 + m * HID + kq;          // h1_{s-2}
        const unsigned short* w2 = (zr ? Urp : Uzp) + HH + (long)n * HID + kq;
        floatx4 acc = gfull2(a1, w1, a2, w2);
        float bv = ldflag(zr ? bhr : bhz, HID + n, flag);
        #pragma unroll
        for (int r = 0; r < 4; ++r) {
          int row = mt * 16 + (lane >> 4) * 4 + r;
          int idx = row * HID + n;
          float v = sigmoidf_(acc[r] + bv);
          if (zr == 0) z1f[idx] = v;
          else         rh1[idx] = f2bf(v * h1f[idx]);
        }
      }
    }
    grid.sync();
    // ================= interval Q =================
    if (blk < 32) {
      if (s < SEQ) {  // A_s: g0 + h0 update
        const int c0 = blk * 32;
        const int mt = wave & 1, nt = wave >> 1;
        const int m = mt * 16 + l15, n = c0 + nt * 16 + l15;
        const unsigned short* a1 = xP + (long)m * (SEQ * HID) + (long)s * HID + kq;
        const unsigned short* w1 = Wgp + (long)n * HID + kq;
        const unsigned short* a2 = rh0 + m * HID + kq;
        const unsigned short* w2 = Ugp + (long)n * HID + kq;
        floatx4 acc = gfull2(a1, w1, a2, w2);
        float bv = ldflag(bhg, n, flag);
        #pragma unroll
        for (int r = 0; r < 4; ++r) {
          int row = mt * 16 + (lane >> 4) * 4 + r;
          int idx = row * HID + n;
          float g = tanhf(acc[r] + bv);
          float z = z0f[idx], hp = h0f[idx];
          float hn = z * hp + (1.f - z) * g;
          h0f[idx] = hn;
          h0b[(s & 1) * NB + idx] = f2bf(hn);
          if (s == SEQ - 1) outw(out, flag, 16777216L + (long)row * 2048 + n, hn);
        }
      }
    } else if (blk < 64) {
      if (s >= 1 && s <= SEQ) {  // B_{s-1}: g1 + h1 update
        const int c0 = (blk - 32) * 32;
        const int mt = wave & 1, nt = wave >> 1;
        const int m = mt * 16 + l15, n = c0 + nt * 16 + l15;
        const unsigned short* a1 = h0b + pPrev + m * HID + kq;           // h0_{s-1}
        const unsigned short* w1 = Wgp + HH + (long)n * HID + kq;
        const unsigned short* a2 = rh1 + m * HID + kq;
        const unsigned short* w2 = Ugp + HH + (long)n * HID + kq;
        floatx4 acc = gfull2(a1, w1, a2, w2);
        float bv = ldflag(bhg, HID + n, flag);
        #pragma unroll
        for (int r = 0; r < 4; ++r) {
          int row = mt * 16 + (lane >> 4) * 4 + r;
          int idx = row * HID + n;
          float g = tanhf(acc[r] + bv);
          float z = z1f[idx], hp = h1f[idx];
          float hn = z * hp + (1.f - z) * g;
          h1f[idx] = hn;
          h1b[((s + 1) & 1) * NB + idx] = f2bf(hn);                      // parity (s-1)&1
          if (s == SEQ) outw(out, flag, 16777216L + (long)row * 2048 + 1024 + n, hn);
        }
      }
    } else {
      if (s >= 2 && wave < 2) {  // Y_{s-2} = h1_{s-2} @ WY^T + bY
        const int c0 = (blk - 64) * 16;
        const int m = wave * 16 + l15, n = c0 + l15;
        const unsigned short* a = h1b + pPrev2 + m * HID + kq;           // h1_{s-2}
        const unsigned short* w = WYp + (long)n * HID + kq;
        floatx4 acc = {0.f, 0.f, 0.f, 0.f};
        #pragma unroll
        for (int k = 0; k < 1024; k += 32)
          acc = __builtin_amdgcn_mfma_f32_16x16x32_bf16(*(const bf16x8*)(a + k),
                                                        *(const bf16x8*)(w + k), acc, 0, 0, 0);
        float bv = ldflag(bY, n, flag);
        const int tY = s - 2;
        #pragma unroll
        for (int r = 0; r < 4; ++r) {
          int brow = wave * 16 + (lane >> 4) * 4 + r;
          long oidx = ((long)brow * SEQ + tY) * HID + n;
          outw(out, flag, oidx, acc[r] + bv);
        }
      }
    }
    grid.sync();
  }
}

extern "C" void kernel_launch(void* const* d_in, const int* in_sizes, int n_in,
                              void* d_out, int out_size, void* d_ws, size_t ws_size,
                              hipStream_t stream) {
  const void* x   = d_in[0];
  const void* h0i = d_in[1];
  const void* Wxz = d_in[2];
  const void* Wxr = d_in[3];
  const void* Wxg = d_in[4];
  const void* Whz = d_in[5];
  const void* Whr = d_in[6];
  const void* Whg = d_in[7];
  const void* bhz = d_in[8];
  const void* bhr = d_in[9];
  const void* bhg = d_in[10];
  const void* WY  = d_in[11];
  const void* bY  = d_in[12];

  char* ws = (char*)d_ws;
  int* flag = (int*)ws;
  float* h0f = (float*)(ws + 1024);
  float* h1f = h0f + NB;
  float* z0f = h1f + NB;
  float* z1f = z0f + NB;
  unsigned short* h0b = (unsigned short*)(z1f + NB);  // 2*NB
  unsigned short* h1b = h0b + 2 * NB;                 // 2*NB
  unsigned short* rh0 = h1b + 2 * NB;
  unsigned short* rh1 = rh0 + NB;
  // conversion area (used only when inputs are fp32)
  unsigned short* xb  = (unsigned short*)(ws + (1 << 20));
  unsigned short* wcv = xb + 16777216L;
  unsigned short* wyc = wcv + 12582912L;

  detect_k<<<1, 64, 0, stream>>>((const unsigned int*)x, flag);
  convert_k<<<2048, 256, 0, stream>>>((const float*)x,
      (const float*)Wxz, (const float*)Wxr, (const float*)Wxg,
      (const float*)Whz, (const float*)Whr, (const float*)Whg,
      (const float*)WY, xb, wcv, wyc, flag);

  void* out = d_out;
  const int* flagc = flag;
  void* args[] = { (void*)&x, (void*)&h0i, (void*)&Wxz, (void*)&Wxr, (void*)&Wxg,
                   (void*)&Whz, (void*)&Whr, (void*)&Whg, (void*)&bhz, (void*)&bhr,
                   (void*)&bhg, (void*)&WY, (void*)&bY, (void*)&out, (void*)&flagc,
                   (void*)&xb, (void*)&wcv, (void*)&wyc,
                   (void*)&h0f, (void*)&h1f, (void*)&z0f, (void*)&z1f,
                   (void*)&h0b, (void*)&h1b, (void*)&rh0, (void*)&rh1 };
  hipLaunchCooperativeKernel((const void*)gru2, dim3(128), dim3(256), args, 0, stream);
}

// Round 3
// 20500.256 us; speedup vs baseline: 1.6700x; 1.6700x over previous
//
#include <hip/hip_runtime.h>
#include <hip/hip_bf16.h>

typedef __bf16 bf16x8 __attribute__((ext_vector_type(8)));
typedef float floatx4 __attribute__((ext_vector_type(4)));

#define HID 1024
#define HH (1024*1024)
#define SEQ 512
#define NB 32768  /* 32*1024 state elements */
#define NBLK 256

__device__ __forceinline__ float bf2f(unsigned short u) {
  union { unsigned int i; float f; } v; v.i = ((unsigned int)u) << 16; return v.f;
}
__device__ __forceinline__ unsigned short f2bf(float f) {
  union { float f; unsigned int i; } v; v.f = f;
  unsigned int i = v.i;
  return (unsigned short)((i + 0x7fffu + ((i >> 16) & 1u)) >> 16);
}
__device__ __forceinline__ float ldflag(const void* p, long i, int flag) {
  return flag ? ((const float*)p)[i] : bf2f(((const unsigned short*)p)[i]);
}
__device__ __forceinline__ void outw(void* out, int flag, long idx, float v) {
  if (flag) ((float*)out)[idx] = v;
  else      ((unsigned short*)out)[idx] = f2bf(v);
}
__device__ __forceinline__ float sigmoidf_(float x) { return 1.0f / (1.0f + __expf(-x)); }

// ---- dtype detection: bf16 (flag=0) vs fp32 (flag=1) ----
__global__ void detect_k(const unsigned int* __restrict__ xw, int* __restrict__ flag) {
  unsigned int w = xw[threadIdx.x];
  int e = (w >> 7) & 0xFF;
  int ok = (e >= 100 && e <= 141) ? 1 : 0;
  unsigned long long m = __ballot(ok);
  if (threadIdx.x == 0) *flag = (__popcll(m) >= 36) ? 0 : 1;
}

// ---- fp32 -> bf16 conversion of x, 6 weight tensors, WY (no-op when flag=0) ----
__global__ void convert_k(const float* __restrict__ x,
                          const float* __restrict__ w0, const float* __restrict__ w1,
                          const float* __restrict__ w2, const float* __restrict__ w3,
                          const float* __restrict__ w4, const float* __restrict__ w5,
                          const float* __restrict__ wy,
                          unsigned short* __restrict__ xb, unsigned short* __restrict__ wc,
                          unsigned short* __restrict__ wyc, const int* __restrict__ flag) {
  if (*flag == 0) return;
  const float* Ws[6] = { w0, w1, w2, w3, w4, w5 };
  const long total = 3801088;
  for (long c = (long)blockIdx.x * 256 + threadIdx.x; c < total; c += (long)gridDim.x * 256) {
    long e = c * 8;
    const float* src; unsigned short* dst; long off;
    if (e < 16777216)      { src = x;  dst = xb;  off = e; }
    else if (e < 29360128) { long r = e - 16777216; int wi = (int)(r >> 21);
                             src = Ws[wi]; dst = wc + (long)wi * 2097152; off = r & 2097151; }
    else                   { src = wy; dst = wyc; off = e - 29360128; }
    float4 a = *(const float4*)(src + off);
    float4 b = *(const float4*)(src + off + 4);
    uint4 o;
    o.x = (unsigned)f2bf(a.x) | ((unsigned)f2bf(a.y) << 16);
    o.y = (unsigned)f2bf(a.z) | ((unsigned)f2bf(a.w) << 16);
    o.z = (unsigned)f2bf(b.x) | ((unsigned)f2bf(b.y) << 16);
    o.w = (unsigned)f2bf(b.z) | ((unsigned)f2bf(b.w) << 16);
    *(uint4*)(dst + off) = o;
  }
}

// ---- grid barrier: monotonic counter, fire-and-forget add + relaxed polling ----
__device__ __forceinline__ void gbar(int* cnt, int target) {
  __syncthreads();
  if (threadIdx.x == 0) {
    __builtin_amdgcn_fence(__ATOMIC_RELEASE, "agent");
    __hip_atomic_fetch_add(cnt, 1, __ATOMIC_RELAXED, __HIP_MEMORY_SCOPE_AGENT);
    while (__hip_atomic_load(cnt, __ATOMIC_RELAXED, __HIP_MEMORY_SCOPE_AGENT) < target)
      __builtin_amdgcn_s_sleep(1);
    __builtin_amdgcn_fence(__ATOMIC_ACQUIRE, "agent");
  }
  __syncthreads();
}

// ---- stage a (W,U) pair of 16 rows x K=1024 each into MFMA-frag-ordered LDS ----
// frag layout (ushort idx): ((m*32 + kc)*64 + L)*8, kc=k>>5, L=((k>>3)&3)*16 | row
__device__ __forceinline__ void stage2(unsigned short* dst,
                                       const unsigned short* __restrict__ s0,
                                       const unsigned short* __restrict__ s1,
                                       int n0, int tid) {
  const unsigned short* srcs[2] = { s0, s1 };
  #pragma unroll
  for (int i = 0; i < 16; ++i) {
    int idx = i * 256 + tid;          // 0..4095: 2 matrices x 16 rows x 128 k8
    int m = idx >> 11;
    int rem = idx & 2047;
    int r = rem >> 7, k8 = rem & 127;
    bf16x8 v = *(const bf16x8*)(srcs[m] + (long)(n0 + r) * HID + k8 * 8);
    int kc = k8 >> 2, L = ((k8 & 3) << 4) | r;
    *(bf16x8*)(dst + (((m * 32 + kc) * 64 + L) << 3)) = v;
  }
}
__device__ __forceinline__ void stage1(unsigned short* dst,
                                       const unsigned short* __restrict__ s0,
                                       int n0, int tid) {
  #pragma unroll
  for (int i = 0; i < 8; ++i) {
    int idx = i * 256 + tid;          // 0..2047
    int r = idx >> 7, k8 = idx & 127;
    bf16x8 v = *(const bf16x8*)(s0 + (long)(n0 + r) * HID + k8 * 8);
    int kc = k8 >> 2, L = ((k8 & 3) << 4) | r;
    *(bf16x8*)(dst + ((kc * 64 + L) << 3)) = v;
  }
}

// ---- per-wave GEMM: A from global (pre-offset), W from frag-ordered LDS ----
__device__ __forceinline__ floatx4 gpair(const unsigned short* __restrict__ a1,
                                         const unsigned short* __restrict__ a2,
                                         const unsigned short* sW, int khalf, int lane) {
  floatx4 acc = {0.f, 0.f, 0.f, 0.f};
  const unsigned short* w1 = sW + (((khalf * 16) * 64 + lane) << 3);
  const unsigned short* w2 = sW + (((32 + khalf * 16) * 64 + lane) << 3);
  #pragma unroll
  for (int j = 0; j < 16; ++j)
    acc = __builtin_amdgcn_mfma_f32_16x16x32_bf16(*(const bf16x8*)(a1 + j * 32),
                                                  *(const bf16x8*)(w1 + j * 512), acc, 0, 0, 0);
  #pragma unroll
  for (int j = 0; j < 16; ++j)
    acc = __builtin_amdgcn_mfma_f32_16x16x32_bf16(*(const bf16x8*)(a2 + j * 32),
                                                  *(const bf16x8*)(w2 + j * 512), acc, 0, 0, 0);
  return acc;
}
__device__ __forceinline__ floatx4 gsingle(const unsigned short* __restrict__ a,
                                           const unsigned short* sW, int khalf, int lane) {
  floatx4 acc = {0.f, 0.f, 0.f, 0.f};
  const unsigned short* w = sW + (((khalf * 16) * 64 + lane) << 3);
  #pragma unroll
  for (int j = 0; j < 16; ++j)
    acc = __builtin_amdgcn_mfma_f32_16x16x32_bf16(*(const bf16x8*)(a + j * 32),
                                                  *(const bf16x8*)(w + j * 512), acc, 0, 0, 0);
  return acc;
}

// Persistent GRU, 256 blocks x 256 threads, LDS-resident weights.
// P roles (blk>>6): 0=z0, 1=r0, 2=z1, 3=r1; 16 cols each ((blk&63)*16).
// Q roles: 0=g0, 1=g1, 2=Y (16 cols, (blk-128)*16), 3=idle.
__global__ void __launch_bounds__(256, 1) gru2(
    const void* __restrict__ x, const void* __restrict__ h0i,
    const void* __restrict__ Wxz, const void* __restrict__ Wxr, const void* __restrict__ Wxg,
    const void* __restrict__ Whz, const void* __restrict__ Whr, const void* __restrict__ Whg,
    const void* __restrict__ bhz, const void* __restrict__ bhr, const void* __restrict__ bhg,
    const void* __restrict__ WY, const void* __restrict__ bY,
    void* __restrict__ out, const int* __restrict__ flagp, int* __restrict__ barCnt,
    const unsigned short* __restrict__ xb, const unsigned short* __restrict__ wcv,
    const unsigned short* __restrict__ wyc,
    float* __restrict__ h0f, float* __restrict__ h1f,
    float* __restrict__ z0f, float* __restrict__ z1f,
    unsigned short* __restrict__ h0b, unsigned short* __restrict__ h1b,
    unsigned short* __restrict__ rh0, unsigned short* __restrict__ rh1)
{
  extern __shared__ char smem[];
  unsigned short* sWP = (unsigned short*)smem;             // 65536 B
  unsigned short* sWQ = (unsigned short*)(smem + 65536);   // 65536 B
  floatx4* red = (floatx4*)(smem + 131072);                // 4096 B

  const int flag = *flagp;
  const int thr  = threadIdx.x;
  const int wave = thr >> 6;
  const int lane = thr & 63;
  const int l15  = lane & 15;
  const int kq   = (lane >> 4) * 8;
  const int blk  = blockIdx.x;
  const int role = blk >> 6;
  const int c0   = (blk & 63) * 16;

  const unsigned short* xP  = flag ? xb                : (const unsigned short*)x;
  const unsigned short* Wzp = flag ? wcv + 0L*2097152  : (const unsigned short*)Wxz;
  const unsigned short* Wrp = flag ? wcv + 1L*2097152  : (const unsigned short*)Wxr;
  const unsigned short* Wgp = flag ? wcv + 2L*2097152  : (const unsigned short*)Wxg;
  const unsigned short* Uzp = flag ? wcv + 3L*2097152  : (const unsigned short*)Whz;
  const unsigned short* Urp = flag ? wcv + 4L*2097152  : (const unsigned short*)Whr;
  const unsigned short* Ugp = flag ? wcv + 5L*2097152  : (const unsigned short*)Whg;
  const unsigned short* WYp = flag ? wyc               : (const unsigned short*)WY;

  // ---- one-time weight staging into LDS (block-local) ----
  {
    long off = (role >> 1) ? (long)HH : 0;
    const unsigned short* s0 = ((role & 1) ? Wrp : Wzp) + off;
    const unsigned short* s1 = ((role & 1) ? Urp : Uzp) + off;
    stage2(sWP, s0, s1, c0, thr);
  }
  if (blk < 128)      stage2(sWQ, Wgp + (blk >= 64 ? (long)HH : 0),
                             Ugp + (blk >= 64 ? (long)HH : 0), c0, thr);
  else if (blk < 192) stage1(sWQ, WYp, (blk - 128) * 16, thr);

  // ---- init hidden state (h_{-1}) into both parity buffers ----
  {
    int gtid = blk * 256 + thr;          // 0..65535
    int layer = gtid >> 15, i = gtid & 32767;
    float v = ldflag(h0i, (long)layer * NB + i, flag);
    unsigned short b = f2bf(v);
    if (layer == 0) { h0f[i] = v; h0b[i] = b; h0b[NB + i] = b; }
    else            { h1f[i] = v; h1b[i] = b; h1b[NB + i] = b; }
  }
  int bt = 0;
  bt += NBLK; gbar(barCnt, bt);

  for (int s = 0; s < SEQ + 2; ++s) {
    const int pPrev  = ((s + 1) & 1) * NB;  // parity slot of h_{s-1}
    const int pPrev2 = (s & 1) * NB;        // parity slot of h_{s-2}
    const int mt = wave & 1, khalf = wave >> 1;
    const int m = mt * 16 + l15;
    const int aoff = kq + khalf * 512;

    // ================= interval P =================
    {
      const int layer = role >> 1, zr = role & 1;
      const bool active = layer ? (s >= 1 && s <= SEQ) : (s < SEQ);
      if (active) {
        const unsigned short *a1, *a2;
        if (layer == 0) {
          a1 = xP + (long)m * (SEQ * HID) + (long)s * HID + aoff;
          a2 = h0b + pPrev + m * HID + aoff;
        } else {
          a1 = h0b + pPrev + m * HID + aoff;
          a2 = h1b + pPrev2 + m * HID + aoff;
        }
        floatx4 acc = gpair(a1, a2, sWP, khalf, lane);
        red[wave * 64 + lane] = acc;
        __syncthreads();
        if (wave < 2) {
          floatx4 ss = red[wave * 64 + lane] + red[(wave + 2) * 64 + lane];
          int n = c0 + l15;
          float bv = ldflag(zr ? bhr : bhz, (long)layer * HID + n, flag);
          #pragma unroll
          for (int r = 0; r < 4; ++r) {
            int row = wave * 16 + (lane >> 4) * 4 + r;
            int idx = row * HID + n;
            float v = sigmoidf_(ss[r] + bv);
            if (role == 0)      z0f[idx] = v;
            else if (role == 1) rh0[idx] = f2bf(v * h0f[idx]);
            else if (role == 2) z1f[idx] = v;
            else                rh1[idx] = f2bf(v * h1f[idx]);
          }
        }
      }
    }
    bt += NBLK; gbar(barCnt, bt);

    // ================= interval Q =================
    if (role == 0) {            // g0 + h0 update (step s)
      if (s < SEQ) {
        const unsigned short* a1 = xP + (long)m * (SEQ * HID) + (long)s * HID + aoff;
        const unsigned short* a2 = rh0 + m * HID + aoff;
        floatx4 acc = gpair(a1, a2, sWQ, khalf, lane);
        red[wave * 64 + lane] = acc;
        __syncthreads();
        if (wave < 2) {
          floatx4 ss = red[wave * 64 + lane] + red[(wave + 2) * 64 + lane];
          int n = c0 + l15;
          float bv = ldflag(bhg, n, flag);
          #pragma unroll
          for (int r = 0; r < 4; ++r) {
            int row = wave * 16 + (lane >> 4) * 4 + r;
            int idx = row * HID + n;
            float g = tanhf(ss[r] + bv);
            float z = z0f[idx], hp = h0f[idx];
            float hn = z * hp + (1.f - z) * g;
            h0f[idx] = hn;
            h0b[(s & 1) * NB + idx] = f2bf(hn);
            if (s == SEQ - 1) outw(out, flag, 16777216L + (long)row * 2048 + n, hn);
          }
        }
      }
    } else if (role == 1) {     // g1 + h1 update (step s-1)
      if (s >= 1 && s <= SEQ) {
        const unsigned short* a1 = h0b + pPrev + m * HID + aoff;
        const unsigned short* a2 = rh1 + m * HID + aoff;
        floatx4 acc = gpair(a1, a2, sWQ, khalf, lane);
        red[wave * 64 + lane] = acc;
        __syncthreads();
        if (wave < 2) {
          floatx4 ss = red[wave * 64 + lane] + red[(wave + 2) * 64 + lane];
          int n = c0 + l15;
          float bv = ldflag(bhg, (long)HID + n, flag);
          #pragma unroll
          for (int r = 0; r < 4; ++r) {
            int row = wave * 16 + (lane >> 4) * 4 + r;
            int idx = row * HID + n;
            float g = tanhf(ss[r] + bv);
            float z = z1f[idx], hp = h1f[idx];
            float hn = z * hp + (1.f - z) * g;
            h1f[idx] = hn;
            h1b[((s + 1) & 1) * NB + idx] = f2bf(hn);
            if (s == SEQ) outw(out, flag, 16777216L + (long)row * 2048 + 1024 + n, hn);
          }
        }
      }
    } else if (role == 2) {     // Y_{s-2}
      if (s >= 2) {
        const int cy = (blk - 128) * 16;
        const unsigned short* a = h1b + pPrev2 + m * HID + aoff;
        floatx4 acc = gsingle(a, sWQ, khalf, lane);
        red[wave * 64 + lane] = acc;
        __syncthreads();
        if (wave < 2) {
          floatx4 ss = red[wave * 64 + lane] + red[(wave + 2) * 64 + lane];
          int n = cy + l15;
          float bv = ldflag(bY, n, flag);
          const int tY = s - 2;
          #pragma unroll
          for (int r = 0; r < 4; ++r) {
            int brow = wave * 16 + (lane >> 4) * 4 + r;
            long oidx = ((long)brow * SEQ + tY) * HID + n;
            outw(out, flag, oidx, ss[r] + bv);
          }
        }
      }
    }
    bt += NBLK; gbar(barCnt, bt);
  }
}

extern "C" void kernel_launch(void* const* d_in, const int* in_sizes, int n_in,
                              void* d_out, int out_size, void* d_ws, size_t ws_size,
                              hipStream_t stream) {
  const void* x   = d_in[0];
  const void* h0i = d_in[1];
  const void* Wxz = d_in[2];
  const void* Wxr = d_in[3];
  const void* Wxg = d_in[4];
  const void* Whz = d_in[5];
  const void* Whr = d_in[6];
  const void* Whg = d_in[7];
  const void* bhz = d_in[8];
  const void* bhr = d_in[9];
  const void* bhg = d_in[10];
  const void* WY  = d_in[11];
  const void* bY  = d_in[12];

  char* ws = (char*)d_ws;
  int* flag   = (int*)ws;
  int* barCnt = (int*)(ws + 512);
  float* h0f = (float*)(ws + 1024);
  float* h1f = h0f + NB;
  float* z0f = h1f + NB;
  float* z1f = z0f + NB;
  unsigned short* h0b = (unsigned short*)(z1f + NB);  // 2*NB
  unsigned short* h1b = h0b + 2 * NB;                 // 2*NB
  unsigned short* rh0 = h1b + 2 * NB;
  unsigned short* rh1 = rh0 + NB;
  unsigned short* xb  = (unsigned short*)(ws + (1 << 20));
  unsigned short* wcv = xb + 16777216L;
  unsigned short* wyc = wcv + 12582912L;

  hipMemsetAsync(barCnt, 0, 64, stream);
  detect_k<<<1, 64, 0, stream>>>((const unsigned int*)x, flag);
  convert_k<<<2048, 256, 0, stream>>>((const float*)x,
      (const float*)Wxz, (const float*)Wxr, (const float*)Wxg,
      (const float*)Whz, (const float*)Whr, (const float*)Whg,
      (const float*)WY, xb, wcv, wyc, flag);

  static int attr_set = 0;
  if (!attr_set) {
    hipFuncSetAttribute((const void*)gru2, hipFuncAttributeMaxDynamicSharedMemorySize, 135168);
    attr_set = 1;
  }

  void* out = d_out;
  const int* flagc = flag;
  int* barc = barCnt;
  void* args[] = { (void*)&x, (void*)&h0i, (void*)&Wxz, (void*)&Wxr, (void*)&Wxg,
                   (void*)&Whz, (void*)&Whr, (void*)&Whg, (void*)&bhz, (void*)&bhr,
                   (void*)&bhg, (void*)&WY, (void*)&bY, (void*)&out, (void*)&flagc,
                   (void*)&barc, (void*)&xb, (void*)&wcv, (void*)&wyc,
                   (void*)&h0f, (void*)&h1f, (void*)&z0f, (void*)&z1f,
                   (void*)&h0b, (void*)&h1b, (void*)&rh0, (void*)&rh1 };
  hipLaunchCooperativeKernel((const void*)gru2, dim3(NBLK), dim3(256), args, 135168, stream);
}